// Round 27
// baseline (127.610 us; speedup 1.0000x reference)
//
#include <hip/hip_runtime.h>

typedef unsigned short u16;
typedef __bf16 bf16x8 __attribute__((ext_vector_type(8)));
typedef float f32x4 __attribute__((ext_vector_type(4)));
typedef float f32x16 __attribute__((ext_vector_type(16)));

#define D_MODEL 1024
#define NH 16
#define DKD 64
#define BB 2
#define SS 2048
// log2(e)/8: folded into Q at projection time
#define QSCL 0.18033688011112042f

#if __has_builtin(__builtin_amdgcn_exp2f)
#define EXP2(x) __builtin_amdgcn_exp2f(x)
#else
#define EXP2(x) exp2f(x)
#endif

__device__ __forceinline__ u16 f2bf(float f) {
  union { float f; unsigned u; } x; x.f = f;
  unsigned r = x.u + 0x7fffu + ((x.u >> 16) & 1u);
  return (u16)(r >> 16);
}

__device__ __forceinline__ void gld16(const u16* g, u16* l) {
  __builtin_amdgcn_global_load_lds((__attribute__((address_space(1))) void*)(g),
                                   (__attribute__((address_space(3))) void*)(l),
                                   16, 0, 0);
}

// ---------------- fused prep: conv (12288 blk) + lw (1 blk) + weight transpose (4096 blk) ----------------
extern "C" __global__ void __launch_bounds__(256) kprep(
    const float* __restrict__ q, const float* __restrict__ k, const float* __restrict__ v,
    const float* __restrict__ wts,
    const float* __restrict__ w0, const float* __restrict__ w1,
    const float* __restrict__ w2, const float* __restrict__ w3,
    u16* __restrict__ xq, u16* __restrict__ xk, u16* __restrict__ xv,
    float* __restrict__ lw,
    u16* __restrict__ o0, u16* __restrict__ o1, u16* __restrict__ o2, u16* __restrict__ o3)
{
  int bx = blockIdx.x;
  if (bx < 12288) {
    // activation fp32 -> bf16
    int z = bx >> 12, blk = bx & 4095;
    const float* s = z == 0 ? q : (z == 1 ? k : v);
    u16* d = z == 0 ? xq : (z == 1 ? xk : xv);
    int i = (blk * 256 + threadIdx.x) * 4;
    float4 val = *(const float4*)(s + i);
    ushort4 o;
    o.x = f2bf(val.x); o.y = f2bf(val.y); o.z = f2bf(val.z); o.w = f2bf(val.w);
    *(ushort4*)(d + i) = o;
  } else if (bx == 12288) {
    // lw = log2(wts + 1e-20) - 16
    int i = threadIdx.x * 16;
    #pragma unroll
    for (int j = 0; j < 16; j += 4) {
      float4 val = *(const float4*)(wts + i + j);
      lw[i + j + 0] = log2f(val.x + 1e-20f) - 16.0f;
      lw[i + j + 1] = log2f(val.y + 1e-20f) - 16.0f;
      lw[i + j + 2] = log2f(val.z + 1e-20f) - 16.0f;
      lw[i + j + 3] = log2f(val.w + 1e-20f) - 16.0f;
    }
  } else {
    // weight transpose + bf16 convert
    int idx = bx - 12289;
    int wi = idx >> 10, rem = idx & 1023;
    int xb = rem & 31, yb = rem >> 5;
    const float* src; u16* dst;
    switch (wi) {
      case 0: src = w0; dst = o0; break;
      case 1: src = w1; dst = o1; break;
      case 2: src = w2; dst = o2; break;
      default: src = w3; dst = o3; break;
    }
    __shared__ float t[32][33];
    int n0 = xb * 32, k0 = yb * 32;
    int tx = threadIdx.x & 31, ty = threadIdx.x >> 5;
    #pragma unroll
    for (int i = 0; i < 32; i += 8)
      t[ty + i][tx] = src[(k0 + ty + i) * D_MODEL + n0 + tx];
    __syncthreads();
    #pragma unroll
    for (int i = 0; i < 32; i += 8)
      dst[(size_t)(n0 + ty + i) * D_MODEL + k0 + tx] = f2bf(t[tx][ty + i]);
  }
}

// ---------------- fused QKV projection: dbuf + XCD-local A-tile reuse + transposed epilogue ----------------
// 1-D grid 768: bid = n*96 + (m + 32*z). bid&7 is n-invariant -> all 8 n-blocks of one
// (m,z) land on the SAME XCD, so the shared A-tile L2-hits after one HBM fetch.
// z==0: Q scaled by QSCL -> (b,h,s,dk). z==1: K -> (b,h,s,dk). z==2: V^T -> (b,h,dk,s).
extern "C" __global__ void __launch_bounds__(256) kgemm_qkv(
    const u16* __restrict__ xq, const u16* __restrict__ xk, const u16* __restrict__ xv,
    const u16* __restrict__ wqt, const u16* __restrict__ wkt, const u16* __restrict__ wvt,
    const float* __restrict__ bq, const float* __restrict__ bk, const float* __restrict__ bv,
    u16* __restrict__ Qb, u16* __restrict__ Kb, u16* __restrict__ Vtt)
{
  __shared__ __align__(16) u16 SH[32768];   // 64KB: 2x(As 16KB + Bs 16KB); epilogue T reuses 34.8KB
  int bid = blockIdx.x;
  int nb = bid / 96, g = bid % 96;
  int mb = g & 31, z = g >> 5;
  const u16* X  = z == 0 ? xq : (z == 1 ? xk : xv);
  const u16* Wt = z == 0 ? wqt : (z == 1 ? wkt : wvt);
  const float* bias = z == 0 ? bq : (z == 1 ? bk : bv);
  int tid = threadIdx.x;
  int m0 = mb * 128, n0 = nb * 128;
  const u16* Ag = X + (size_t)m0 * D_MODEL;
  const u16* Bg = Wt + (size_t)n0 * D_MODEL;

  int lane = tid & 63, lr = lane & 15, lg = lane >> 4;
  int w = tid >> 6, wr = w >> 1, wc = w & 1;
  int sr7 = lr & 7;

  f32x4 zero = {0.f, 0.f, 0.f, 0.f};
  f32x4 acc[4][4];
  #pragma unroll
  for (int i = 0; i < 4; ++i)
    #pragma unroll
    for (int j = 0; j < 4; ++j) acc[i][j] = zero;

#define GSTAGE(k0, base) do { \
    _Pragma("unroll") \
    for (int c = 0; c < 4; ++c) { \
      int idx = tid + c * 256; \
      int row = idx >> 3, c3 = idx & 7; \
      int col = (c3 ^ (row & 7)) * 8; \
      gld16(Ag + row * D_MODEL + (k0) + col, SH + (base) + idx * 8); \
      gld16(Bg + row * D_MODEL + (k0) + col, SH + (base) + 8192 + idx * 8); \
    } \
  } while (0)

  GSTAGE(0, 0);
  for (int ks = 0; ks < 16; ++ks) {
    asm volatile("s_waitcnt vmcnt(0) lgkmcnt(0)" ::: "memory");
    __builtin_amdgcn_s_barrier();
    __builtin_amdgcn_sched_barrier(0);
    if (ks + 1 < 16) GSTAGE((ks + 1) * 64, ((ks + 1) & 1) * 16384);
    const u16* Asp = SH + (ks & 1) * 16384;
    const u16* Bsp = Asp + 8192;
    #pragma unroll
    for (int kk = 0; kk < 2; ++kk) {
      bf16x8 af[4], bfr[4];
      #pragma unroll
      for (int mi = 0; mi < 4; ++mi)
        af[mi] = *(const bf16x8*)(Asp + (wr * 64 + mi * 16 + lr) * 64 + (((kk * 4 + lg) ^ sr7) * 8));
      #pragma unroll
      for (int nj = 0; nj < 4; ++nj)
        bfr[nj] = *(const bf16x8*)(Bsp + (wc * 64 + nj * 16 + lr) * 64 + (((kk * 4 + lg) ^ sr7) * 8));
      #pragma unroll
      for (int mi = 0; mi < 4; ++mi)
        #pragma unroll
        for (int nj = 0; nj < 4; ++nj)
          acc[mi][nj] = __builtin_amdgcn_mfma_f32_16x16x32_bf16(af[mi], bfr[nj], acc[mi][nj], 0, 0, 0);
    }
  }
#undef GSTAGE
  __syncthreads();   // all waves done with slots before epilogue reuses SH

  float scl = (z == 0) ? QSCL : 1.0f;
  if (z == 2) {
    // T2[nl][ml] (nl = local n = dk', ml = local m = s): j-contiguous -> ushort4 writes
    #pragma unroll
    for (int mi = 0; mi < 4; ++mi)
      #pragma unroll
      for (int nj = 0; nj < 4; ++nj) {
        int nl = wc * 64 + nj * 16 + lr;
        float bs = bias[n0 + nl];
        int ml = wr * 64 + mi * 16 + lg * 4;
        ushort4 o;
        o.x = f2bf(acc[mi][nj][0] + bs);
        o.y = f2bf(acc[mi][nj][1] + bs);
        o.z = f2bf(acc[mi][nj][2] + bs);
        o.w = f2bf(acc[mi][nj][3] + bs);
        *(ushort4*)&SH[nl * 136 + ml] = o;
      }
    __syncthreads();
    #pragma unroll
    for (int p = 0; p < 8; ++p) {
      int idx = p * 256 + tid;
      int nl = idx >> 4, c = idx & 15;
      int nn = n0 + nl;
      int h = nn >> 6, dk = nn & 63;
      int m = m0 + c * 8;
      int b = m0 >> 11;                      // tile never spans batch boundary
      bf16x8 vv = *(const bf16x8*)&SH[nl * 136 + c * 8];
      *(bf16x8*)&Vtt[(((size_t)(b * NH + h)) * DKD + dk) * SS + (m & 2047)] = vv;
    }
  } else {
    u16* dst = (z == 0) ? Qb : Kb;
    #pragma unroll
    for (int mi = 0; mi < 4; ++mi)
      #pragma unroll
      for (int nj = 0; nj < 4; ++nj) {
        int nl = wc * 64 + nj * 16 + lr;
        float bs = bias[n0 + nl];
        int ml = wr * 64 + mi * 16 + lg * 4;
        #pragma unroll
        for (int j = 0; j < 4; ++j)
          SH[(ml + j) * 136 + nl] = f2bf((acc[mi][nj][j] + bs) * scl);
      }
    __syncthreads();
    #pragma unroll
    for (int p = 0; p < 8; ++p) {
      int idx = p * 256 + tid;
      int ml = idx >> 4, c = idx & 15;
      int m = m0 + ml;
      int b = m >> 11, s = m & 2047;
      int nn = n0 + c * 8;
      int h = nn >> 6, dk = nn & 63;
      bf16x8 vv = *(const bf16x8*)&SH[ml * 136 + c * 8];
      *(bf16x8*)&dst[(((size_t)(b * NH + h)) * SS + s) * DKD + dk] = vv;
    }
  }
}

// ---------------- output projection: 64x128 tile, dbuf, XCD-local A-tile reuse ----------------
extern "C" __global__ void __launch_bounds__(256) kgemm_o(
    const u16* __restrict__ AO, const u16* __restrict__ wot,
    const float* __restrict__ bo, float* __restrict__ out)
{
  __shared__ __align__(16) u16 SH[24576];   // 48KB: 2x(As 8KB + Bs 16KB)
  int tid = threadIdx.x;
  int lane = tid & 63, lr = lane & 15, lg = lane >> 4;
  int w = tid >> 6, wr = w & 1, wc = w >> 1;   // wave: 32 M-rows x 64 N-cols
  int sr7 = lr & 7;
  int bid = blockIdx.x;
  int nb = bid >> 6, mb = bid & 63;
  int m0 = mb * 64, n0 = nb * 128;
  const u16* Ag = AO + (size_t)m0 * D_MODEL;
  const u16* Bg = wot + (size_t)n0 * D_MODEL;
  f32x4 zero = {0.f, 0.f, 0.f, 0.f};
  f32x4 acc[2][4];
  #pragma unroll
  for (int i = 0; i < 2; ++i)
    #pragma unroll
    for (int j = 0; j < 4; ++j) acc[i][j] = zero;

#define OSTAGE(k0, base) do { \
    _Pragma("unroll") \
    for (int c = 0; c < 2; ++c) { \
      int idx = tid + c * 256; \
      int row = idx >> 3, c3 = idx & 7; \
      int col = (c3 ^ (row & 7)) * 8; \
      gld16(Ag + row * D_MODEL + (k0) + col, SH + (base) + idx * 8); \
    } \
    _Pragma("unroll") \
    for (int c = 0; c < 4; ++c) { \
      int idx = tid + c * 256; \
      int row = idx >> 3, c3 = idx & 7; \
      int col = (c3 ^ (row & 7)) * 8; \
      gld16(Bg + row * D_MODEL + (k0) + col, SH + (base) + 4096 + idx * 8); \
    } \
  } while (0)

  OSTAGE(0, 0);
  for (int ks = 0; ks < 16; ++ks) {
    asm volatile("s_waitcnt vmcnt(0) lgkmcnt(0)" ::: "memory");
    __builtin_amdgcn_s_barrier();
    __builtin_amdgcn_sched_barrier(0);
    if (ks + 1 < 16) OSTAGE((ks + 1) * 64, ((ks + 1) & 1) * 12288);
    const u16* Asp = SH + (ks & 1) * 12288;
    const u16* Bsp = Asp + 4096;
    #pragma unroll
    for (int kk = 0; kk < 2; ++kk) {
      bf16x8 af[2], bfr[4];
      #pragma unroll
      for (int mi = 0; mi < 2; ++mi)
        af[mi] = *(const bf16x8*)(Asp + (wr * 32 + mi * 16 + lr) * 64 + (((kk * 4 + lg) ^ sr7) * 8));
      #pragma unroll
      for (int nj = 0; nj < 4; ++nj)
        bfr[nj] = *(const bf16x8*)(Bsp + (wc * 64 + nj * 16 + lr) * 64 + (((kk * 4 + lg) ^ sr7) * 8));
      #pragma unroll
      for (int mi = 0; mi < 2; ++mi)
        #pragma unroll
        for (int nj = 0; nj < 4; ++nj)
          acc[mi][nj] = __builtin_amdgcn_mfma_f32_16x16x32_bf16(af[mi], bfr[nj], acc[mi][nj], 0, 0, 0);
    }
  }
#undef OSTAGE

  #pragma unroll
  for (int mi = 0; mi < 2; ++mi)
    #pragma unroll
    for (int nj = 0; nj < 4; ++nj) {
      int n = n0 + wc * 64 + nj * 16 + lr;
      float bs = bo[n];
      #pragma unroll
      for (int j = 0; j < 4; ++j) {
        int m = m0 + wr * 32 + mi * 16 + lg * 4 + j;
        out[(size_t)m * D_MODEL + n] = acc[mi][nj][j] + bs;
      }
    }
}

// ---------------- flash attention: ring-4, one barrier/iter, conflict-free swizzle,
// lsum via ones-MFMA (R27: shift 32 VALU adds/tile to the 27%-busy MFMA pipe; each
// lane ends with the FULL per-parity denominator -> epilogue shfl deleted) ----------------
#define FSW(r) ((((r) >> 3) ^ (r)) & 7)
extern "C" __global__ void __launch_bounds__(512, 4) kattn(
    const u16* __restrict__ Qb, const u16* __restrict__ Kb, const u16* __restrict__ Vt,
    const float* __restrict__ lw2, u16* __restrict__ AO)
{
  __shared__ __align__(16) char smem[4 * 16384 + 8192];  // 4 K/V slots + lwf
  float* lwf = (float*)(smem + 65536);

  int tid = threadIdx.x, lane = tid & 63, w = tid >> 6;  // w 0..7
  int lq = lane & 31, hi = lane >> 5;
  int qw = w & 3, par = w >> 2;

  // XCD-clustered decode: each XCD owns 4 heads x all 16 q-tiles (K/V L2-resident)
  int n = blockIdx.x;                  // 0..511
  int xcd = n & 7, slot = n >> 3;
  int bh = xcd + 8 * (slot >> 4);
  int q0 = (slot & 15) * 128;
  int b = bh >> 4, h = bh & 15;

  const u16* Qg = Qb + ((size_t)bh * SS + q0 + qw * 32) * DKD;
  const u16* Kg = Kb + (size_t)bh * SS * DKD;
  const u16* Vg = Vt + (size_t)bh * DKD * SS;   // rows = dk, cols = s
  const float* lwb = lw2 + b * SS;

  // stage lw row into LDS (512 threads x 1 float4)
  *(float4*)&lwf[tid * 4] = *(const float4*)(lwb + tid * 4);

  // Q B-frags: B[k = kc*16 + hi*8 + i][q = lq]
  bf16x8 qf[4];
  #pragma unroll
  for (int kc = 0; kc < 4; ++kc)
    qf[kc] = *(const bf16x8*)(Qg + lq * DKD + kc * 16 + hi * 8);

  // all-ones bf16 A-fragment for the lsum MFMA (C[r][q] = sum_k Pb[k][q])
  union { u16 s[8]; bf16x8 v; } onesu;
  #pragma unroll
  for (int i = 0; i < 8; ++i) onesu.s[i] = 0x3F80;
  bf16x8 onesv = onesu.v;

  f32x16 acco[2] = {};
  f32x16 acc_l = {};

  // staging: LDS[row][c3] = Global[row][c3 ^ FSW(row)] (linear dest for gld16)
  int srow = tid >> 3, sc = ((tid & 7) ^ FSW(srow)) * 8;
  int fsw_lo = FSW(lq), fsw_hi = FSW(32 + lq);

#define KSLOT(sl) ((u16*)(smem + (sl) * 16384))
#define VSLOT(sl) ((u16*)(smem + (sl) * 16384 + 8192))
#define STAGE(t, sl) do { \
    gld16(Kg + (size_t)((t) * 64 + srow) * DKD + sc, KSLOT(sl) + tid * 8); \
    gld16(Vg + (size_t)srow * SS + (t) * 64 + sc, VSLOT(sl) + tid * 8); \
  } while (0)

  STAGE(0, 0); STAGE(1, 1);          // pair 0 -> slots 0,1
  for (int i = 0; i < 16; ++i) {
    asm volatile("s_waitcnt vmcnt(0) lgkmcnt(0)" ::: "memory");
    __builtin_amdgcn_s_barrier();
    __builtin_amdgcn_sched_barrier(0);
    int tn = 2 * i + 2;
    if (tn < 32) { STAGE(tn, tn & 3); STAGE(tn + 1, (tn + 1) & 3); }

    int t = 2 * i + par;
    int sl = t & 3;
    const u16* Kp = KSLOT(sl);
    const u16* Vp = VSLOT(sl);
    int kv0 = t * 64;

    // ---- St init from lw: row(reg r) = (r&3) + 8*(r>>2) + 4*hi ----
    f32x16 st[2];
    #pragma unroll
    for (int nh = 0; nh < 2; ++nh)
      #pragma unroll
      for (int g = 0; g < 4; ++g) {
        f32x4 lv = *(const f32x4*)&lwf[kv0 + nh * 32 + 4 * hi + 8 * g];
        st[nh][4 * g + 0] = lv[0]; st[nh][4 * g + 1] = lv[1];
        st[nh][4 * g + 2] = lv[2]; st[nh][4 * g + 3] = lv[3];
      }

    // ---- St += K * Q^T ----
    __builtin_amdgcn_s_setprio(1);
    #pragma unroll
    for (int kc = 0; kc < 4; ++kc) {
      bf16x8 kf0 = *(const bf16x8*)&Kp[(lq) * 64      + (((kc * 2 + hi) ^ fsw_lo) * 8)];
      bf16x8 kf1 = *(const bf16x8*)&Kp[(32 + lq) * 64 + (((kc * 2 + hi) ^ fsw_hi) * 8)];
      st[0] = __builtin_amdgcn_mfma_f32_32x32x16_bf16(kf0, qf[kc], st[0], 0, 0, 0);
      st[1] = __builtin_amdgcn_mfma_f32_32x32x16_bf16(kf1, qf[kc], st[1], 0, 0, 0);
    }
    __builtin_amdgcn_s_setprio(0);

    // ---- p = exp2(st) (single v_exp_f32); pack pairs (lsum via ones-MFMA below) ----
    unsigned wd[2][8];
    #pragma unroll
    for (int nh = 0; nh < 2; ++nh)
      #pragma unroll
      for (int r2 = 0; r2 < 8; ++r2) {
        float plo = EXP2(st[nh][2 * r2]);
        float phi = EXP2(st[nh][2 * r2 + 1]);
        union { unsigned u; __bf16 b2[2]; } cv;
        cv.b2[0] = (__bf16)plo; cv.b2[1] = (__bf16)phi;
        wd[nh][r2] = cv.u;
      }

    // ---- Pb[c] B-frags via permlane32_swap ----
    bf16x8 Pb[4];
    #pragma unroll
    for (int c = 0; c < 4; ++c) {
      int nh = c >> 1, j0 = 4 * (c & 1);
      auto s1 = __builtin_amdgcn_permlane32_swap(wd[nh][j0 + 0], wd[nh][j0 + 2], false, false);
      auto s2 = __builtin_amdgcn_permlane32_swap(wd[nh][j0 + 1], wd[nh][j0 + 3], false, false);
      union { unsigned u[4]; bf16x8 v; } pb;
      pb.u[0] = s1[0]; pb.u[1] = s2[0]; pb.u[2] = s1[1]; pb.u[3] = s2[1];
      Pb[c] = pb.v;
    }

    // ---- O^T += V^T * Pb ; lsum += ones * Pb (MFMA pipe) ----
    __builtin_amdgcn_s_setprio(1);
    #pragma unroll
    for (int c = 0; c < 4; ++c) {
      bf16x8 vf0 = *(const bf16x8*)&Vp[(lq) * 64      + (((c * 2 + hi) ^ fsw_lo) * 8)];
      bf16x8 vf1 = *(const bf16x8*)&Vp[(32 + lq) * 64 + (((c * 2 + hi) ^ fsw_hi) * 8)];
      acc_l   = __builtin_amdgcn_mfma_f32_32x32x16_bf16(onesv, Pb[c], acc_l, 0, 0, 0);
      acco[0] = __builtin_amdgcn_mfma_f32_32x32x16_bf16(vf0, Pb[c], acco[0], 0, 0, 0);
      acco[1] = __builtin_amdgcn_mfma_f32_32x32x16_bf16(vf1, Pb[c], acco[1], 0, 0, 0);
    }
    __builtin_amdgcn_s_setprio(0);
  }
#undef STAGE

  // ---- epilogue: acc_l[0] = FULL per-parity denominator for q=lq; combine parity
  // partners via LDS (stride 34 f32), par=0 stores ----
  __syncthreads();
  float lsum_part = acc_l[0];
  float* comb = (float*)smem;          // slots dead; 4*64*34*4 = 34.8KB < 72KB
  int coff = (qw * 64 + lane) * 34;
  if (par == 1) {
    #pragma unroll
    for (int d = 0; d < 2; ++d)
      #pragma unroll
      for (int g = 0; g < 8; ++g)
        *(float2*)&comb[coff + (d * 8 + g) * 2] = make_float2(acco[d][2 * g], acco[d][2 * g + 1]);
    comb[coff + 32] = lsum_part;
  }
  __syncthreads();
  if (par == 0) {
    #pragma unroll
    for (int d = 0; d < 2; ++d)
      #pragma unroll
      for (int g = 0; g < 8; ++g) {
        float2 v = *(const float2*)&comb[coff + (d * 8 + g) * 2];
        acco[d][2 * g] += v.x; acco[d][2 * g + 1] += v.y;
      }
    float lsum = lsum_part + comb[coff + 32];
    float inv = 1.0f / lsum;
    int s = q0 + qw * 32 + lq;
    size_t base = ((size_t)b * SS + s) * D_MODEL + h * DKD;
    #pragma unroll
    for (int dh = 0; dh < 2; ++dh)
      #pragma unroll
      for (int g = 0; g < 4; ++g) {
        ushort4 o;
        o.x = f2bf(acco[dh][4 * g + 0] * inv);
        o.y = f2bf(acco[dh][4 * g + 1] * inv);
        o.z = f2bf(acco[dh][4 * g + 2] * inv);
        o.w = f2bf(acco[dh][4 * g + 3] * inv);
        *(ushort4*)(AO + base + dh * 32 + 4 * hi + 8 * g) = o;
      }
  }
#undef KSLOT
#undef VSLOT
}

extern "C" void kernel_launch(void* const* d_in, const int* in_sizes, int n_in,
                              void* d_out, int out_size, void* d_ws, size_t ws_size,
                              hipStream_t stream) {
  const float* query = (const float*)d_in[0];
  const float* key_  = (const float*)d_in[1];
  const float* value = (const float*)d_in[2];
  const float* wts   = (const float*)d_in[3];
  const float* wq = (const float*)d_in[4];
  const float* bq = (const float*)d_in[5];
  const float* wk = (const float*)d_in[6];
  const float* bk = (const float*)d_in[7];
  const float* wv = (const float*)d_in[8];
  const float* bv = (const float*)d_in[9];
  const float* wo = (const float*)d_in[10];
  const float* bo = (const float*)d_in[11];
  float* out = (float*)d_out;

  char* ws = (char*)d_ws;
  const size_t MB = 1024 * 1024;
  u16* Xq  = (u16*)(ws + 0 * MB);
  u16* Xk  = (u16*)(ws + 8 * MB);
  u16* Xv  = (u16*)(ws + 16 * MB);
  u16* WqT = (u16*)(ws + 24 * MB);
  u16* WkT = (u16*)(ws + 26 * MB);
  u16* WvT = (u16*)(ws + 28 * MB);
  u16* WoT = (u16*)(ws + 30 * MB);
  u16* Qb  = (u16*)(ws + 32 * MB);
  u16* Kb  = (u16*)(ws + 40 * MB);
  u16* VtT = (u16*)(ws + 48 * MB);   // V^T (b,h,dk,s), written directly by kgemm_qkv z==2
  u16* AO  = (u16*)(ws + 56 * MB);
  float* lwbuf = (float*)(ws + 64 * MB);

  kprep<<<16385, 256, 0, stream>>>(query, key_, value, wts, wq, wk, wv, wo,
                                   Xq, Xk, Xv, lwbuf, WqT, WkT, WvT, WoT);
  kgemm_qkv<<<768, 256, 0, stream>>>(Xq, Xk, Xv, WqT, WkT, WvT, bq, bk, bv, Qb, Kb, VtT);
  kattn<<<512, 512, 0, stream>>>(Qb, Kb, VtT, lwbuf, AO);
  kgemm_o<<<512, 256, 0, stream>>>(AO, WoT, bo, out);
}

// Round 28
// 115.064 us; speedup vs baseline: 1.1090x; 1.1090x over previous
//
#include <hip/hip_runtime.h>

typedef unsigned short u16;
typedef __bf16 bf16x8 __attribute__((ext_vector_type(8)));
typedef float f32x4 __attribute__((ext_vector_type(4)));
typedef float f32x16 __attribute__((ext_vector_type(16)));

#define D_MODEL 1024
#define NH 16
#define DKD 64
#define BB 2
#define SS 2048
// log2(e)/8: folded into Q at projection time
#define QSCL 0.18033688011112042f

#if __has_builtin(__builtin_amdgcn_exp2f)
#define EXP2(x) __builtin_amdgcn_exp2f(x)
#else
#define EXP2(x) exp2f(x)
#endif

__device__ __forceinline__ u16 f2bf(float f) {
  union { float f; unsigned u; } x; x.f = f;
  unsigned r = x.u + 0x7fffu + ((x.u >> 16) & 1u);
  return (u16)(r >> 16);
}

__device__ __forceinline__ void gld16(const u16* g, u16* l) {
  __builtin_amdgcn_global_load_lds((__attribute__((address_space(1))) void*)(g),
                                   (__attribute__((address_space(3))) void*)(l),
                                   16, 0, 0);
}

// ---------------- fused prep: conv (12288 blk) + lw (1 blk) + weight transpose (4096 blk) ----------------
extern "C" __global__ void __launch_bounds__(256) kprep(
    const float* __restrict__ q, const float* __restrict__ k, const float* __restrict__ v,
    const float* __restrict__ wts,
    const float* __restrict__ w0, const float* __restrict__ w1,
    const float* __restrict__ w2, const float* __restrict__ w3,
    u16* __restrict__ xq, u16* __restrict__ xk, u16* __restrict__ xv,
    float* __restrict__ lw,
    u16* __restrict__ o0, u16* __restrict__ o1, u16* __restrict__ o2, u16* __restrict__ o3)
{
  int bx = blockIdx.x;
  if (bx < 12288) {
    // activation fp32 -> bf16
    int z = bx >> 12, blk = bx & 4095;
    const float* s = z == 0 ? q : (z == 1 ? k : v);
    u16* d = z == 0 ? xq : (z == 1 ? xk : xv);
    int i = (blk * 256 + threadIdx.x) * 4;
    float4 val = *(const float4*)(s + i);
    ushort4 o;
    o.x = f2bf(val.x); o.y = f2bf(val.y); o.z = f2bf(val.z); o.w = f2bf(val.w);
    *(ushort4*)(d + i) = o;
  } else if (bx == 12288) {
    // lw = log2(wts + 1e-20) - 16
    int i = threadIdx.x * 16;
    #pragma unroll
    for (int j = 0; j < 16; j += 4) {
      float4 val = *(const float4*)(wts + i + j);
      lw[i + j + 0] = log2f(val.x + 1e-20f) - 16.0f;
      lw[i + j + 1] = log2f(val.y + 1e-20f) - 16.0f;
      lw[i + j + 2] = log2f(val.z + 1e-20f) - 16.0f;
      lw[i + j + 3] = log2f(val.w + 1e-20f) - 16.0f;
    }
  } else {
    // weight transpose + bf16 convert
    int idx = bx - 12289;
    int wi = idx >> 10, rem = idx & 1023;
    int xb = rem & 31, yb = rem >> 5;
    const float* src; u16* dst;
    switch (wi) {
      case 0: src = w0; dst = o0; break;
      case 1: src = w1; dst = o1; break;
      case 2: src = w2; dst = o2; break;
      default: src = w3; dst = o3; break;
    }
    __shared__ float t[32][33];
    int n0 = xb * 32, k0 = yb * 32;
    int tx = threadIdx.x & 31, ty = threadIdx.x >> 5;
    #pragma unroll
    for (int i = 0; i < 32; i += 8)
      t[ty + i][tx] = src[(k0 + ty + i) * D_MODEL + n0 + tx];
    __syncthreads();
    #pragma unroll
    for (int i = 0; i < 32; i += 8)
      dst[(size_t)(n0 + ty + i) * D_MODEL + k0 + tx] = f2bf(t[tx][ty + i]);
  }
}

// ---------------- fused QKV projection: dbuf + XCD-local A-tile reuse + transposed epilogue ----------------
// 1-D grid 768: bid = n*96 + (m + 32*z). bid&7 is n-invariant -> all 8 n-blocks of one
// (m,z) land on the SAME XCD, so the shared A-tile L2-hits after one HBM fetch.
// z==0: Q scaled by QSCL -> (b,h,s,dk). z==1: K -> (b,h,s,dk). z==2: V^T -> (b,h,dk,s).
extern "C" __global__ void __launch_bounds__(256) kgemm_qkv(
    const u16* __restrict__ xq, const u16* __restrict__ xk, const u16* __restrict__ xv,
    const u16* __restrict__ wqt, const u16* __restrict__ wkt, const u16* __restrict__ wvt,
    const float* __restrict__ bq, const float* __restrict__ bk, const float* __restrict__ bv,
    u16* __restrict__ Qb, u16* __restrict__ Kb, u16* __restrict__ Vtt)
{
  __shared__ __align__(16) u16 SH[32768];   // 64KB: 2x(As 16KB + Bs 16KB); epilogue T reuses 34.8KB
  int bid = blockIdx.x;
  int nb = bid / 96, g = bid % 96;
  int mb = g & 31, z = g >> 5;
  const u16* X  = z == 0 ? xq : (z == 1 ? xk : xv);
  const u16* Wt = z == 0 ? wqt : (z == 1 ? wkt : wvt);
  const float* bias = z == 0 ? bq : (z == 1 ? bk : bv);
  int tid = threadIdx.x;
  int m0 = mb * 128, n0 = nb * 128;
  const u16* Ag = X + (size_t)m0 * D_MODEL;
  const u16* Bg = Wt + (size_t)n0 * D_MODEL;

  int lane = tid & 63, lr = lane & 15, lg = lane >> 4;
  int w = tid >> 6, wr = w >> 1, wc = w & 1;
  int sr7 = lr & 7;

  f32x4 zero = {0.f, 0.f, 0.f, 0.f};
  f32x4 acc[4][4];
  #pragma unroll
  for (int i = 0; i < 4; ++i)
    #pragma unroll
    for (int j = 0; j < 4; ++j) acc[i][j] = zero;

#define GSTAGE(k0, base) do { \
    _Pragma("unroll") \
    for (int c = 0; c < 4; ++c) { \
      int idx = tid + c * 256; \
      int row = idx >> 3, c3 = idx & 7; \
      int col = (c3 ^ (row & 7)) * 8; \
      gld16(Ag + row * D_MODEL + (k0) + col, SH + (base) + idx * 8); \
      gld16(Bg + row * D_MODEL + (k0) + col, SH + (base) + 8192 + idx * 8); \
    } \
  } while (0)

  GSTAGE(0, 0);
  for (int ks = 0; ks < 16; ++ks) {
    asm volatile("s_waitcnt vmcnt(0) lgkmcnt(0)" ::: "memory");
    __builtin_amdgcn_s_barrier();
    __builtin_amdgcn_sched_barrier(0);
    if (ks + 1 < 16) GSTAGE((ks + 1) * 64, ((ks + 1) & 1) * 16384);
    const u16* Asp = SH + (ks & 1) * 16384;
    const u16* Bsp = Asp + 8192;
    #pragma unroll
    for (int kk = 0; kk < 2; ++kk) {
      bf16x8 af[4], bfr[4];
      #pragma unroll
      for (int mi = 0; mi < 4; ++mi)
        af[mi] = *(const bf16x8*)(Asp + (wr * 64 + mi * 16 + lr) * 64 + (((kk * 4 + lg) ^ sr7) * 8));
      #pragma unroll
      for (int nj = 0; nj < 4; ++nj)
        bfr[nj] = *(const bf16x8*)(Bsp + (wc * 64 + nj * 16 + lr) * 64 + (((kk * 4 + lg) ^ sr7) * 8));
      #pragma unroll
      for (int mi = 0; mi < 4; ++mi)
        #pragma unroll
        for (int nj = 0; nj < 4; ++nj)
          acc[mi][nj] = __builtin_amdgcn_mfma_f32_16x16x32_bf16(af[mi], bfr[nj], acc[mi][nj], 0, 0, 0);
    }
  }
#undef GSTAGE
  __syncthreads();   // all waves done with slots before epilogue reuses SH

  float scl = (z == 0) ? QSCL : 1.0f;
  if (z == 2) {
    // T2[nl][ml] (nl = local n = dk', ml = local m = s): j-contiguous -> ushort4 writes
    #pragma unroll
    for (int mi = 0; mi < 4; ++mi)
      #pragma unroll
      for (int nj = 0; nj < 4; ++nj) {
        int nl = wc * 64 + nj * 16 + lr;
        float bs = bias[n0 + nl];
        int ml = wr * 64 + mi * 16 + lg * 4;
        ushort4 o;
        o.x = f2bf(acc[mi][nj][0] + bs);
        o.y = f2bf(acc[mi][nj][1] + bs);
        o.z = f2bf(acc[mi][nj][2] + bs);
        o.w = f2bf(acc[mi][nj][3] + bs);
        *(ushort4*)&SH[nl * 136 + ml] = o;
      }
    __syncthreads();
    #pragma unroll
    for (int p = 0; p < 8; ++p) {
      int idx = p * 256 + tid;
      int nl = idx >> 4, c = idx & 15;
      int nn = n0 + nl;
      int h = nn >> 6, dk = nn & 63;
      int m = m0 + c * 8;
      int b = m0 >> 11;                      // tile never spans batch boundary
      bf16x8 vv = *(const bf16x8*)&SH[nl * 136 + c * 8];
      *(bf16x8*)&Vtt[(((size_t)(b * NH + h)) * DKD + dk) * SS + (m & 2047)] = vv;
    }
  } else {
    u16* dst = (z == 0) ? Qb : Kb;
    #pragma unroll
    for (int mi = 0; mi < 4; ++mi)
      #pragma unroll
      for (int nj = 0; nj < 4; ++nj) {
        int nl = wc * 64 + nj * 16 + lr;
        float bs = bias[n0 + nl];
        int ml = wr * 64 + mi * 16 + lg * 4;
        #pragma unroll
        for (int j = 0; j < 4; ++j)
          SH[(ml + j) * 136 + nl] = f2bf((acc[mi][nj][j] + bs) * scl);
      }
    __syncthreads();
    #pragma unroll
    for (int p = 0; p < 8; ++p) {
      int idx = p * 256 + tid;
      int ml = idx >> 4, c = idx & 15;
      int m = m0 + ml;
      int b = m >> 11, s = m & 2047;
      int nn = n0 + c * 8;
      int h = nn >> 6, dk = nn & 63;
      bf16x8 vv = *(const bf16x8*)&SH[ml * 136 + c * 8];
      *(bf16x8*)&dst[(((size_t)(b * NH + h)) * SS + s) * DKD + dk] = vv;
    }
  }
}

// ---------------- output projection: 64x128 tile, dbuf, XCD-local A-tile reuse ----------------
extern "C" __global__ void __launch_bounds__(256) kgemm_o(
    const u16* __restrict__ AO, const u16* __restrict__ wot,
    const float* __restrict__ bo, float* __restrict__ out)
{
  __shared__ __align__(16) u16 SH[24576];   // 48KB: 2x(As 8KB + Bs 16KB)
  int tid = threadIdx.x;
  int lane = tid & 63, lr = lane & 15, lg = lane >> 4;
  int w = tid >> 6, wr = w & 1, wc = w >> 1;   // wave: 32 M-rows x 64 N-cols
  int sr7 = lr & 7;
  int bid = blockIdx.x;
  int nb = bid >> 6, mb = bid & 63;
  int m0 = mb * 64, n0 = nb * 128;
  const u16* Ag = AO + (size_t)m0 * D_MODEL;
  const u16* Bg = wot + (size_t)n0 * D_MODEL;
  f32x4 zero = {0.f, 0.f, 0.f, 0.f};
  f32x4 acc[2][4];
  #pragma unroll
  for (int i = 0; i < 2; ++i)
    #pragma unroll
    for (int j = 0; j < 4; ++j) acc[i][j] = zero;

#define OSTAGE(k0, base) do { \
    _Pragma("unroll") \
    for (int c = 0; c < 2; ++c) { \
      int idx = tid + c * 256; \
      int row = idx >> 3, c3 = idx & 7; \
      int col = (c3 ^ (row & 7)) * 8; \
      gld16(Ag + row * D_MODEL + (k0) + col, SH + (base) + idx * 8); \
    } \
    _Pragma("unroll") \
    for (int c = 0; c < 4; ++c) { \
      int idx = tid + c * 256; \
      int row = idx >> 3, c3 = idx & 7; \
      int col = (c3 ^ (row & 7)) * 8; \
      gld16(Bg + row * D_MODEL + (k0) + col, SH + (base) + 4096 + idx * 8); \
    } \
  } while (0)

  OSTAGE(0, 0);
  for (int ks = 0; ks < 16; ++ks) {
    asm volatile("s_waitcnt vmcnt(0) lgkmcnt(0)" ::: "memory");
    __builtin_amdgcn_s_barrier();
    __builtin_amdgcn_sched_barrier(0);
    if (ks + 1 < 16) OSTAGE((ks + 1) * 64, ((ks + 1) & 1) * 12288);
    const u16* Asp = SH + (ks & 1) * 12288;
    const u16* Bsp = Asp + 4096;
    #pragma unroll
    for (int kk = 0; kk < 2; ++kk) {
      bf16x8 af[2], bfr[4];
      #pragma unroll
      for (int mi = 0; mi < 2; ++mi)
        af[mi] = *(const bf16x8*)(Asp + (wr * 32 + mi * 16 + lr) * 64 + (((kk * 4 + lg) ^ sr7) * 8));
      #pragma unroll
      for (int nj = 0; nj < 4; ++nj)
        bfr[nj] = *(const bf16x8*)(Bsp + (wc * 64 + nj * 16 + lr) * 64 + (((kk * 4 + lg) ^ sr7) * 8));
      #pragma unroll
      for (int mi = 0; mi < 2; ++mi)
        #pragma unroll
        for (int nj = 0; nj < 4; ++nj)
          acc[mi][nj] = __builtin_amdgcn_mfma_f32_16x16x32_bf16(af[mi], bfr[nj], acc[mi][nj], 0, 0, 0);
    }
  }
#undef OSTAGE

  #pragma unroll
  for (int mi = 0; mi < 2; ++mi)
    #pragma unroll
    for (int nj = 0; nj < 4; ++nj) {
      int n = n0 + wc * 64 + nj * 16 + lr;
      float bs = bo[n];
      #pragma unroll
      for (int j = 0; j < 4; ++j) {
        int m = m0 + wr * 32 + mi * 16 + lg * 4 + j;
        out[(size_t)m * D_MODEL + n] = acc[mi][nj][j] + bs;
      }
    }
}

// ---------------- flash attention: ring-4, one barrier/iter, conflict-free swizzle (R26 best) ----------------
// R27 falsified: ones-MFMA lsum (+16 VGPR f32x16 acc) induced scratch traffic and a
// serial MFMA chain -> 50->67us. The 32 scalar lsum adds are effectively free. KEEP R26.
#define FSW(r) ((((r) >> 3) ^ (r)) & 7)
extern "C" __global__ void __launch_bounds__(512, 4) kattn(
    const u16* __restrict__ Qb, const u16* __restrict__ Kb, const u16* __restrict__ Vt,
    const float* __restrict__ lw2, u16* __restrict__ AO)
{
  __shared__ __align__(16) char smem[4 * 16384 + 8192];  // 4 K/V slots + lwf
  float* lwf = (float*)(smem + 65536);

  int tid = threadIdx.x, lane = tid & 63, w = tid >> 6;  // w 0..7
  int lq = lane & 31, hi = lane >> 5;
  int qw = w & 3, par = w >> 2;

  // XCD-clustered decode: each XCD owns 4 heads x all 16 q-tiles (K/V L2-resident)
  int n = blockIdx.x;                  // 0..511
  int xcd = n & 7, slot = n >> 3;
  int bh = xcd + 8 * (slot >> 4);
  int q0 = (slot & 15) * 128;
  int b = bh >> 4, h = bh & 15;

  const u16* Qg = Qb + ((size_t)bh * SS + q0 + qw * 32) * DKD;
  const u16* Kg = Kb + (size_t)bh * SS * DKD;
  const u16* Vg = Vt + (size_t)bh * DKD * SS;   // rows = dk, cols = s
  const float* lwb = lw2 + b * SS;

  // stage lw row into LDS (512 threads x 1 float4)
  *(float4*)&lwf[tid * 4] = *(const float4*)(lwb + tid * 4);

  // Q B-frags: B[k = kc*16 + hi*8 + i][q = lq]
  bf16x8 qf[4];
  #pragma unroll
  for (int kc = 0; kc < 4; ++kc)
    qf[kc] = *(const bf16x8*)(Qg + lq * DKD + kc * 16 + hi * 8);

  f32x16 acco[2] = {};
  float lsp[4] = {0.f, 0.f, 0.f, 0.f};

  // staging: LDS[row][c3] = Global[row][c3 ^ FSW(row)] (linear dest for gld16)
  int srow = tid >> 3, sc = ((tid & 7) ^ FSW(srow)) * 8;
  int fsw_lo = FSW(lq), fsw_hi = FSW(32 + lq);

#define KSLOT(sl) ((u16*)(smem + (sl) * 16384))
#define VSLOT(sl) ((u16*)(smem + (sl) * 16384 + 8192))
#define STAGE(t, sl) do { \
    gld16(Kg + (size_t)((t) * 64 + srow) * DKD + sc, KSLOT(sl) + tid * 8); \
    gld16(Vg + (size_t)srow * SS + (t) * 64 + sc, VSLOT(sl) + tid * 8); \
  } while (0)

  STAGE(0, 0); STAGE(1, 1);          // pair 0 -> slots 0,1
  for (int i = 0; i < 16; ++i) {
    asm volatile("s_waitcnt vmcnt(0) lgkmcnt(0)" ::: "memory");
    __builtin_amdgcn_s_barrier();
    __builtin_amdgcn_sched_barrier(0);
    int tn = 2 * i + 2;
    if (tn < 32) { STAGE(tn, tn & 3); STAGE(tn + 1, (tn + 1) & 3); }

    int t = 2 * i + par;
    int sl = t & 3;
    const u16* Kp = KSLOT(sl);
    const u16* Vp = VSLOT(sl);
    int kv0 = t * 64;

    // ---- St init from lw: row(reg r) = (r&3) + 8*(r>>2) + 4*hi ----
    f32x16 st[2];
    #pragma unroll
    for (int nh = 0; nh < 2; ++nh)
      #pragma unroll
      for (int g = 0; g < 4; ++g) {
        f32x4 lv = *(const f32x4*)&lwf[kv0 + nh * 32 + 4 * hi + 8 * g];
        st[nh][4 * g + 0] = lv[0]; st[nh][4 * g + 1] = lv[1];
        st[nh][4 * g + 2] = lv[2]; st[nh][4 * g + 3] = lv[3];
      }

    // ---- St += K * Q^T ----
    __builtin_amdgcn_s_setprio(1);
    #pragma unroll
    for (int kc = 0; kc < 4; ++kc) {
      bf16x8 kf0 = *(const bf16x8*)&Kp[(lq) * 64      + (((kc * 2 + hi) ^ fsw_lo) * 8)];
      bf16x8 kf1 = *(const bf16x8*)&Kp[(32 + lq) * 64 + (((kc * 2 + hi) ^ fsw_hi) * 8)];
      st[0] = __builtin_amdgcn_mfma_f32_32x32x16_bf16(kf0, qf[kc], st[0], 0, 0, 0);
      st[1] = __builtin_amdgcn_mfma_f32_32x32x16_bf16(kf1, qf[kc], st[1], 0, 0, 0);
    }
    __builtin_amdgcn_s_setprio(0);

    // ---- p = exp2(st) (single v_exp_f32); per-lane lsum partials; pack pairs ----
    unsigned wd[2][8];
    #pragma unroll
    for (int nh = 0; nh < 2; ++nh)
      #pragma unroll
      for (int r2 = 0; r2 < 8; ++r2) {
        float plo = EXP2(st[nh][2 * r2]);
        float phi = EXP2(st[nh][2 * r2 + 1]);
        lsp[r2 & 3] += plo + phi;
        union { unsigned u; __bf16 b2[2]; } cv;
        cv.b2[0] = (__bf16)plo; cv.b2[1] = (__bf16)phi;
        wd[nh][r2] = cv.u;
      }

    // ---- Pb[c] B-frags via permlane32_swap ----
    bf16x8 Pb[4];
    #pragma unroll
    for (int c = 0; c < 4; ++c) {
      int nh = c >> 1, j0 = 4 * (c & 1);
      auto s1 = __builtin_amdgcn_permlane32_swap(wd[nh][j0 + 0], wd[nh][j0 + 2], false, false);
      auto s2 = __builtin_amdgcn_permlane32_swap(wd[nh][j0 + 1], wd[nh][j0 + 3], false, false);
      union { unsigned u[4]; bf16x8 v; } pb;
      pb.u[0] = s1[0]; pb.u[1] = s2[0]; pb.u[2] = s1[1]; pb.u[3] = s2[1];
      Pb[c] = pb.v;
    }

    // ---- O^T += V^T * Pb ----
    __builtin_amdgcn_s_setprio(1);
    #pragma unroll
    for (int c = 0; c < 4; ++c) {
      bf16x8 vf0 = *(const bf16x8*)&Vp[(lq) * 64      + (((c * 2 + hi) ^ fsw_lo) * 8)];
      bf16x8 vf1 = *(const bf16x8*)&Vp[(32 + lq) * 64 + (((c * 2 + hi) ^ fsw_hi) * 8)];
      acco[0] = __builtin_amdgcn_mfma_f32_32x32x16_bf16(vf0, Pb[c], acco[0], 0, 0, 0);
      acco[1] = __builtin_amdgcn_mfma_f32_32x32x16_bf16(vf1, Pb[c], acco[1], 0, 0, 0);
    }
    __builtin_amdgcn_s_setprio(0);
  }
#undef STAGE

  // ---- epilogue: combine parity partners via LDS (stride 34 f32), par=0 stores ----
  __syncthreads();
  float lsum_part = (lsp[0] + lsp[1]) + (lsp[2] + lsp[3]);
  float* comb = (float*)smem;          // slots dead; 4*64*34*4 = 34.8KB < 72KB
  int coff = (qw * 64 + lane) * 34;
  if (par == 1) {
    #pragma unroll
    for (int d = 0; d < 2; ++d)
      #pragma unroll
      for (int g = 0; g < 8; ++g)
        *(float2*)&comb[coff + (d * 8 + g) * 2] = make_float2(acco[d][2 * g], acco[d][2 * g + 1]);
    comb[coff + 32] = lsum_part;
  }
  __syncthreads();
  if (par == 0) {
    #pragma unroll
    for (int d = 0; d < 2; ++d)
      #pragma unroll
      for (int g = 0; g < 8; ++g) {
        float2 v = *(const float2*)&comb[coff + (d * 8 + g) * 2];
        acco[d][2 * g] += v.x; acco[d][2 * g + 1] += v.y;
      }
    lsum_part += comb[coff + 32];
    float lsum = lsum_part + __shfl_xor(lsum_part, 32);
    float inv = 1.0f / lsum;
    int s = q0 + qw * 32 + lq;
    size_t base = ((size_t)b * SS + s) * D_MODEL + h * DKD;
    #pragma unroll
    for (int dh = 0; dh < 2; ++dh)
      #pragma unroll
      for (int g = 0; g < 4; ++g) {
        ushort4 o;
        o.x = f2bf(acco[dh][4 * g + 0] * inv);
        o.y = f2bf(acco[dh][4 * g + 1] * inv);
        o.z = f2bf(acco[dh][4 * g + 2] * inv);
        o.w = f2bf(acco[dh][4 * g + 3] * inv);
        *(ushort4*)(AO + base + dh * 32 + 4 * hi + 8 * g) = o;
      }
  }
#undef KSLOT
#undef VSLOT
}

extern "C" void kernel_launch(void* const* d_in, const int* in_sizes, int n_in,
                              void* d_out, int out_size, void* d_ws, size_t ws_size,
                              hipStream_t stream) {
  const float* query = (const float*)d_in[0];
  const float* key_  = (const float*)d_in[1];
  const float* value = (const float*)d_in[2];
  const float* wts   = (const float*)d_in[3];
  const float* wq = (const float*)d_in[4];
  const float* bq = (const float*)d_in[5];
  const float* wk = (const float*)d_in[6];
  const float* bk = (const float*)d_in[7];
  const float* wv = (const float*)d_in[8];
  const float* bv = (const float*)d_in[9];
  const float* wo = (const float*)d_in[10];
  const float* bo = (const float*)d_in[11];
  float* out = (float*)d_out;

  char* ws = (char*)d_ws;
  const size_t MB = 1024 * 1024;
  u16* Xq  = (u16*)(ws + 0 * MB);
  u16* Xk  = (u16*)(ws + 8 * MB);
  u16* Xv  = (u16*)(ws + 16 * MB);
  u16* WqT = (u16*)(ws + 24 * MB);
  u16* WkT = (u16*)(ws + 26 * MB);
  u16* WvT = (u16*)(ws + 28 * MB);
  u16* WoT = (u16*)(ws + 30 * MB);
  u16* Qb  = (u16*)(ws + 32 * MB);
  u16* Kb  = (u16*)(ws + 40 * MB);
  u16* VtT = (u16*)(ws + 48 * MB);   // V^T (b,h,dk,s), written directly by kgemm_qkv z==2
  u16* AO  = (u16*)(ws + 56 * MB);
  float* lwbuf = (float*)(ws + 64 * MB);

  kprep<<<16385, 256, 0, stream>>>(query, key_, value, wts, wq, wk, wv, wo,
                                   Xq, Xk, Xv, lwbuf, WqT, WkT, WvT, WoT);
  kgemm_qkv<<<768, 256, 0, stream>>>(Xq, Xk, Xv, WqT, WkT, WvT, bq, bk, bv, Qb, Kb, VtT);
  kattn<<<512, 512, 0, stream>>>(Qb, Kb, VtT, lwbuf, AO);
  kgemm_o<<<512, 256, 0, stream>>>(AO, WoT, bo, out);
}